// Round 8
// baseline (205.222 us; speedup 1.0000x reference)
//
#include <hip/hip_runtime.h>
#include <cstdint>

#define MDIM 8192
#define NDIM 8192
#define QPR  (NDIM / 2)     // packed int32 entries per row = 4096
#define ABPR (NDIM / 64)    // absmax blocks per row = 128
#define ROWS_PER_BLOCK 16
#define HGRAN 2048          // column-pair granules per half-block (4096 cols)
#define CHUNKS 8            // 8 chunks x 512 cols = 4096 cols per half

typedef _Float16 half2_t __attribute__((ext_vector_type(2)));
typedef uint32_t u32x4   __attribute__((ext_vector_type(4)));

// ---- byte-parallel fp4 decode via v_perm_b32 ----
// codebook magnitudes k=0..7: {0, 1/192, 2/3, 1, 1/3, 1/2, 1/6, 1/4}
// f16 hi-byte table: 0x00,0x1D,0x39,0x3C,0x35,0x38,0x31,0x34 (k=0..7)
// f16 lo-byte is 0x55 exactly for k=1,2,4,6; sign = nibble bit3 -> f16 bit15.
// perm convention: sel byte 0-3 -> src1 bytes, 4-7 -> src0 bytes.
__device__ __forceinline__ void dec8(u32x4 qA, uint32_t out[4]) {
#if __has_builtin(__builtin_amdgcn_perm)
  // qweight int32 values are 0..255 -> bytes 1-3 are zero; pack 4 bytes.
  uint32_t D  = qA.x | (qA.y << 8) | (qA.z << 16) | (qA.w << 24);
  uint32_t L  = D & 0x0F0F0F0Fu;          // lo nibbles (odd columns)
  uint32_t H  = (D >> 4) & 0x0F0F0F0Fu;   // hi nibbles (even columns)
  uint32_t Lm = L & 0x07070707u;
  uint32_t Hm = H & 0x07070707u;
  uint32_t hbL = __builtin_amdgcn_perm(0x34313835u, 0x3C391D00u, Lm)
               | ((L << 4) & 0x80808080u);
  uint32_t hbH = __builtin_amdgcn_perm(0x34313835u, 0x3C391D00u, Hm)
               | ((H << 4) & 0x80808080u);
  uint32_t lbL = __builtin_amdgcn_perm(0x00550055u, 0x00555500u, Lm);
  uint32_t lbH = __builtin_amdgcn_perm(0x00550055u, 0x00555500u, Hm);
  // interleave bytes -> f16 halfwords: (lb,hb) little-endian per nibble
  uint32_t A01 = __builtin_amdgcn_perm(hbH, lbH, 0x05010400u);
  uint32_t A23 = __builtin_amdgcn_perm(hbH, lbH, 0x07030602u);
  uint32_t B01 = __builtin_amdgcn_perm(hbL, lbL, 0x05010400u);
  uint32_t B23 = __builtin_amdgcn_perm(hbL, lbL, 0x07030602u);
  out[0] = __builtin_amdgcn_perm(B01, A01, 0x05040100u);
  out[1] = __builtin_amdgcn_perm(B01, A01, 0x07060302u);
  out[2] = __builtin_amdgcn_perm(B23, A23, 0x05040100u);
  out[3] = __builtin_amdgcn_perm(B23, A23, 0x07060302u);
#else
  // scalar fallback (previous rounds' path)
  for (int i = 0; i < 4; ++i) {
    uint32_t b = (i == 0) ? qA.x : (i == 1) ? qA.y : (i == 2) ? qA.z : qA.w;
    uint32_t r = 0;
    for (int n = 0; n < 2; ++n) {
      uint32_t idx = (n == 0) ? ((b >> 4) & 15u) : (b & 15u);
      uint32_t k   = idx & 7u;
      uint32_t hb  = (uint32_t)(0x343138353C391D00ull >> (k * 8)) & 0xFFu;
      uint32_t lb  = (0u - (hb & 1u)) & 0x55u;
      uint32_t f   = (hb << 8) | lb | ((idx & 8u) << 12);
      r |= f << (16 * n);
    }
    out[i] = r;
  }
#endif
}

__device__ __forceinline__ float fdot2(uint32_t w, uint32_t x, float c) {
#if __has_builtin(__builtin_amdgcn_fdot2)
  return __builtin_amdgcn_fdot2(__builtin_bit_cast(half2_t, w),
                                __builtin_bit_cast(half2_t, x), c, false);
#else
  half2_t wh = __builtin_bit_cast(half2_t, w);
  half2_t xh = __builtin_bit_cast(half2_t, x);
  return c + (float)wh.x * (float)xh.x + (float)wh.y * (float)xh.y;
#endif
}

// XOR swizzle on 16B granules; spreads 64 lanes uniformly over bank groups.
__device__ __forceinline__ uint32_t swz(uint32_t g) { return g ^ ((g >> 3) & 7u); }

// d_out is poisoned 0xAA; seed it with bias so the main kernel can atomicAdd.
__global__ void bias_init(const float* __restrict__ bias, float* __restrict__ out) {
  int i = blockIdx.x * 256 + threadIdx.x;          // 32768 threads
  out[i] = bias[i & (MDIM - 1)];
}

__global__ __launch_bounds__(256, 4) void fp4gemv(
    const float* __restrict__ x, const uint32_t* __restrict__ qw,
    const float* __restrict__ am, const float* __restrict__ bias,
    float* __restrict__ out) {
  // x staged as packed-f16 column pairs for this block's half of the columns.
  __shared__ uint32_t xs[HGRAN * 4];
  // absmax for this block's 16 rows x 64 column-blocks; pad 65 for banks.
  __shared__ float amx[ROWS_PER_BLOCK * 65];

  const int half = blockIdx.x & 1;       // which half of the columns
  const int mblk = blockIdx.x >> 1;      // which 16-row group

  // ---- stage x -> LDS ----
#pragma unroll 4
  for (int it = 0; it < 8; ++it) {
    int p = threadIdx.x + it * 256;                 // local granule 0..2047
    int c = 2 * (half * HGRAN + p);                 // global column
    float2 v0 = *(const float2*)(x + 0 * NDIM + c);
    float2 v1 = *(const float2*)(x + 1 * NDIM + c);
    float2 v2 = *(const float2*)(x + 2 * NDIM + c);
    float2 v3 = *(const float2*)(x + 3 * NDIM + c);
    union { _Float16 h[2]; uint32_t u; } c0, c1, c2, c3;
    c0.h[0] = (_Float16)v0.x; c0.h[1] = (_Float16)v0.y;
    c1.h[0] = (_Float16)v1.x; c1.h[1] = (_Float16)v1.y;
    c2.h[0] = (_Float16)v2.x; c2.h[1] = (_Float16)v2.y;
    c3.h[0] = (_Float16)v3.x; c3.h[1] = (_Float16)v3.y;
    uint4 w; w.x = c0.u; w.y = c1.u; w.z = c2.u; w.w = c3.u;
    *(uint4*)&xs[swz((uint32_t)p) * 4] = w;
  }
  // ---- stage absmax -> LDS ----
  {
    int idx = threadIdx.x * 4;                      // 1024 floats total
    int r = idx >> 6, j = idx & 63;
    const float* ap = am + (size_t)(mblk * ROWS_PER_BLOCK + r) * ABPR + half * 64 + j;
    float4 v = *(const float4*)ap;
    amx[r * 65 + j + 0] = v.x;
    amx[r * 65 + j + 1] = v.y;
    amx[r * 65 + j + 2] = v.z;
    amx[r * 65 + j + 3] = v.w;
  }
  __syncthreads();

  // ---- main: wave owns 4 rows; each global load = 64 lanes x 16B = 1KB
  //      contiguous from one row; plain loads (nt measured neutral). ----
  const int lane = threadIdx.x & 63;
  const int wv   = threadIdx.x >> 6;
  const int m0   = mblk * ROWS_PER_BLOCK + wv * 4;

  const u32x4* qb0 = (const u32x4*)(qw + (size_t)(m0 + 0) * QPR + half * 2048);
  const u32x4* qb1 = (const u32x4*)(qw + (size_t)(m0 + 1) * QPR + half * 2048);
  const u32x4* qb2 = (const u32x4*)(qw + (size_t)(m0 + 2) * QPR + half * 2048);
  const u32x4* qb3 = (const u32x4*)(qw + (size_t)(m0 + 3) * QPR + half * 2048);

  float acc[4][4];
#pragma unroll
  for (int j = 0; j < 4; ++j)
#pragma unroll
    for (int b = 0; b < 4; ++b) acc[j][b] = 0.f;

  // ring of 8 loads = 2 chunks ahead
  u32x4 ring[8];
  ring[0] = qb0[lane];        ring[1] = qb1[lane];
  ring[2] = qb2[lane];        ring[3] = qb3[lane];
  ring[4] = qb0[64 + lane];   ring[5] = qb1[64 + lane];
  ring[6] = qb2[64 + lane];   ring[7] = qb3[64 + lane];

#pragma unroll
  for (int k = 0; k < CHUNKS; ++k) {
    // x granules for chunk k (shared by all 4 rows): lane's 8 columns
    const int g0 = 256 * k + 4 * lane;
    uint4 x0 = *(const uint4*)&xs[swz((uint32_t)(g0 + 0)) * 4];
    uint4 x1 = *(const uint4*)&xs[swz((uint32_t)(g0 + 1)) * 4];
    uint4 x2 = *(const uint4*)&xs[swz((uint32_t)(g0 + 2)) * 4];
    uint4 x3 = *(const uint4*)&xs[swz((uint32_t)(g0 + 3)) * 4];

    const int sb = 8 * k + (lane >> 3);             // absmax block for lane's cols
    const int kp = (k + 2 < CHUNKS) ? k + 2 : CHUNKS - 1;   // clamped prefetch

#pragma unroll
    for (int j = 0; j < 4; ++j) {
      const int r = (4 * k + j) & 7;
      u32x4 qA = ring[r];
      const u32x4* qbj = (j == 0) ? qb0 : (j == 1) ? qb1 : (j == 2) ? qb2 : qb3;
      ring[r] = qbj[64 * kp + lane];                // tail re-reads are L2 hits

      uint32_t h[4];
      dec8(qA, h);                                  // 8 weights as 4 half2s

      float sA = amx[(wv * 4 + j) * 65 + sb];       // LDS, lgkmcnt only

      float t0, t1, t2, t3;
      t0 = fdot2(h[0], x0.x, 0.f); t0 = fdot2(h[1], x1.x, t0);
      t0 = fdot2(h[2], x2.x, t0);  t0 = fdot2(h[3], x3.x, t0);
      t1 = fdot2(h[0], x0.y, 0.f); t1 = fdot2(h[1], x1.y, t1);
      t1 = fdot2(h[2], x2.y, t1);  t1 = fdot2(h[3], x3.y, t1);
      t2 = fdot2(h[0], x0.z, 0.f); t2 = fdot2(h[1], x1.z, t2);
      t2 = fdot2(h[2], x2.z, t2);  t2 = fdot2(h[3], x3.z, t2);
      t3 = fdot2(h[0], x0.w, 0.f); t3 = fdot2(h[1], x1.w, t3);
      t3 = fdot2(h[2], x2.w, t3);  t3 = fdot2(h[3], x3.w, t3);

      acc[j][0] = fmaf(sA, t0, acc[j][0]);
      acc[j][1] = fmaf(sA, t1, acc[j][1]);
      acc[j][2] = fmaf(sA, t2, acc[j][2]);
      acc[j][3] = fmaf(sA, t3, acc[j][3]);
    }
  }

  // 64-lane butterfly reduce each of the 16 accumulators
#pragma unroll
  for (int j = 0; j < 4; ++j)
#pragma unroll
    for (int b = 0; b < 4; ++b)
#pragma unroll
      for (int off = 32; off > 0; off >>= 1)
        acc[j][b] += __shfl_xor(acc[j][b], off);

  if (lane == 0) {
#pragma unroll
    for (int j = 0; j < 4; ++j) {
#pragma unroll
      for (int b = 0; b < 4; ++b)
        atomicAdd(&out[b * MDIM + (m0 + j)], acc[j][b]);
    }
  }
}

extern "C" void kernel_launch(void* const* d_in, const int* in_sizes, int n_in,
                              void* d_out, int out_size, void* d_ws, size_t ws_size,
                              hipStream_t stream) {
  const float*    x    = (const float*)d_in[0];
  const uint32_t* qwp  = (const uint32_t*)d_in[1];   // int32 values 0..255
  const float*    am   = (const float*)d_in[2];
  // d_in[3] = code (fixed FP4 codebook, folded into dec8 tables)
  const float*    bias = (const float*)d_in[4];
  float*          out  = (float*)d_out;

  bias_init<<<dim3((4 * MDIM) / 256), dim3(256), 0, stream>>>(bias, out);
  fp4gemv<<<dim3((MDIM / ROWS_PER_BLOCK) * 2), dim3(256), 0, stream>>>(
      x, qwp, am, bias, out);
}